// Round 5
// baseline (493.760 us; speedup 1.0000x reference)
//
#include <hip/hip_runtime.h>
#include <hip/hip_bf16.h>

typedef unsigned short u16;
typedef __attribute__((ext_vector_type(8))) short short8;
typedef __attribute__((ext_vector_type(4))) float f32x4;

#define B_ 8
#define V_ 64
#define T_ 256
#define T1_ 257
#define D_ 256
#define H_ 8
#define DH_ 32

__device__ __forceinline__ u16 f2bf(float f){
  union { float f; unsigned int u; } v; v.f = f;
  unsigned int u = v.u;
  return (u16)((u + 0x7fffu + ((u >> 16) & 1u)) >> 16);
}

// ---------------- kernel 0: weights -> bf16, + zero xsum ----------------
__global__ void k0_conv(const float* __restrict__ wqkv, const float* __restrict__ wproj,
                        u16* __restrict__ wv, u16* __restrict__ wp, float* __restrict__ xsum){
  int i = blockIdx.x * 256 + threadIdx.x;   // 512 blocks -> 131072
  if (i < 65536) wv[i] = f2bf(wqkv[131072 + i]);     // rows 512..767 = Wv
  else           wp[i - 65536] = f2bf(wproj[i - 65536]);
  xsum[i] = 0.f;
}

// ---------------- kernel 1: LN stats + masked xn-sum (r1 config) ----------------
__global__ void k1_ln(const float* __restrict__ x, const int* __restrict__ mask,
                      const float* __restrict__ lnw, const float* __restrict__ lnb,
                      float* __restrict__ musig, float* __restrict__ xsum){
  int bv = blockIdx.x;
  int tid = threadIdx.x;
  int lane = tid & 63, wid = tid >> 6;
  int half = lane >> 5, l32 = lane & 31;
  int c8 = l32 * 8;
  __shared__ float xsred[4][512];
  float4 w0 = *(const float4*)&lnw[c8], w1 = *(const float4*)&lnw[c8 + 4];
  float4 b0 = *(const float4*)&lnb[c8], b1 = *(const float4*)&lnb[c8 + 4];
  float xs[8];
  #pragma unroll
  for (int j = 0; j < 8; ++j) xs[j] = 0.f;
  for (int p = blockIdx.y * 4 + wid; p < 129; p += 16){
    int t = p * 2 + half;
    bool valid = (t < T1_);
    float4 a0 = {0.f,0.f,0.f,0.f}, a1 = {0.f,0.f,0.f,0.f};
    if (valid){
      const float* gp = &x[((long)bv * T1_ + t) * D_ + c8];
      a0 = *(const float4*)gp; a1 = *(const float4*)(gp + 4);
    }
    float s  = a0.x + a0.y + a0.z + a0.w + a1.x + a1.y + a1.z + a1.w;
    float s2 = a0.x*a0.x + a0.y*a0.y + a0.z*a0.z + a0.w*a0.w
             + a1.x*a1.x + a1.y*a1.y + a1.z*a1.z + a1.w*a1.w;
    #pragma unroll
    for (int off = 1; off < 32; off <<= 1){
      s  += __shfl_xor(s,  off, 64);
      s2 += __shfl_xor(s2, off, 64);
    }
    float mu   = s * (1.f / 256.f);
    float var  = s2 * (1.f / 256.f) - mu * mu;
    float rstd = rsqrtf(var + 1e-5f);
    if (valid){
      if (l32 == 0){
        musig[((long)bv * T1_ + t) * 2]     = mu;
        musig[((long)bv * T1_ + t) * 2 + 1] = rstd;
      }
      int m = (t == 0) ? 1 : mask[bv * T_ + (t - 1)];
      if (m){
        xs[0] += (a0.x - mu) * rstd * w0.x + b0.x;
        xs[1] += (a0.y - mu) * rstd * w0.y + b0.y;
        xs[2] += (a0.z - mu) * rstd * w0.z + b0.z;
        xs[3] += (a0.w - mu) * rstd * w0.w + b0.w;
        xs[4] += (a1.x - mu) * rstd * w1.x + b1.x;
        xs[5] += (a1.y - mu) * rstd * w1.y + b1.y;
        xs[6] += (a1.z - mu) * rstd * w1.z + b1.z;
        xs[7] += (a1.w - mu) * rstd * w1.w + b1.w;
      }
    }
  }
  #pragma unroll
  for (int j = 0; j < 8; ++j) xsred[wid][half * 256 + c8 + j] = xs[j];
  __syncthreads();
  float r = xsred[0][tid] + xsred[1][tid] + xsred[2][tid] + xsred[3][tid]
          + xsred[0][256 + tid] + xsred[1][256 + tid] + xsred[2][256 + tid] + xsred[3][256 + tid];
  if (tid < 256) atomicAdd(&xsum[bv * D_ + tid], r);
  else           atomicAdd(&xsum[bv * D_ + tid - 256], 0.f);
}

// ---------------- kernel 2a: q,k projections (tiny) ----------------
__global__ void k2a_qk(const float* __restrict__ x, const int* __restrict__ mask,
                       const float* __restrict__ lnw, const float* __restrict__ lnb,
                       const float* __restrict__ wqkv,
                       const float* __restrict__ musig, const float* __restrict__ xsum,
                       float* __restrict__ qout, float* __restrict__ kout){
  int bv = blockIdx.x, tid = threadIdx.x;
  int lane = tid & 63, wid = tid >> 6;
  __shared__ __align__(16) float xn0[D_];
  __shared__ __align__(16) float xs[D_];
  __shared__ float redc[4];
  int s = mask[bv * T_ + tid];
  #pragma unroll
  for (int off = 32; off >= 1; off >>= 1) s += __shfl_down(s, off, 64);
  if (lane == 0) redc[wid] = (float)s;
  __syncthreads();
  float cnt = 1.f + redc[0] + redc[1] + redc[2] + redc[3];
  float mu = musig[((long)bv * T1_) * 2], rstd = musig[((long)bv * T1_) * 2 + 1];
  xn0[tid] = (x[((long)bv * T1_) * D_ + tid] - mu) * rstd * lnw[tid] + lnb[tid];
  xs[tid]  = xsum[bv * D_ + tid] * (1.f / cnt);
  __syncthreads();
  float4 xq = *(const float4*)&xn0[lane * 4];
  float4 xk = *(const float4*)&xs[lane * 4];
  int e0 = (blockIdx.y * 4 + wid) * 16;
  for (int i = 0; i < 16; ++i){
    int e = e0 + i;
    float4 wq4 = *(const float4*)&wqkv[(long)e * D_ + lane * 4];
    float4 wk4 = *(const float4*)&wqkv[(long)(256 + e) * D_ + lane * 4];
    float sq = xq.x*wq4.x + xq.y*wq4.y + xq.z*wq4.z + xq.w*wq4.w;
    float sk = xk.x*wk4.x + xk.y*wk4.y + xk.z*wk4.z + xk.w*wk4.w;
    #pragma unroll
    for (int off = 32; off >= 1; off >>= 1){
      sq += __shfl_down(sq, off, 64);
      sk += __shfl_down(sk, off, 64);
    }
    if (lane == 0){ qout[bv * D_ + e] = sq; kout[bv * D_ + e] = sk; }
  }
}

// ---------------- kernel 2b: 64x64 attention per (b,h) (r1 config) ----------------
__global__ void k2b_attn(const float* __restrict__ q, const float* __restrict__ k,
                         u16* __restrict__ attn){
  int bh = blockIdx.x; int b = bh >> 3, h = bh & 7;
  int tid = threadIdx.x;
  int lane = tid & 63, wid = tid >> 6;
  __shared__ float qs[64][33], ks[64][33];
  #pragma unroll
  for (int j = 0; j < 2; ++j){
    int i4 = tid * 2 + j;
    int r = i4 >> 3, c4 = (i4 & 7) * 4;
    float4 vq = *(const float4*)&q[((long)(b * V_ + r)) * D_ + h * DH_ + c4];
    float4 vk = *(const float4*)&k[((long)(b * V_ + r)) * D_ + h * DH_ + c4];
    qs[r][c4] = vq.x; qs[r][c4+1] = vq.y; qs[r][c4+2] = vq.z; qs[r][c4+3] = vq.w;
    ks[r][c4] = vk.x; ks[r][c4+1] = vk.y; ks[r][c4+2] = vk.z; ks[r][c4+3] = vk.w;
  }
  __syncthreads();
  const float scale = 0.17677669529663687f;  // 1/sqrt(32)
  for (int i = 0; i < 16; ++i){
    int qr = i * 4 + wid;
    float a = 0.f;
    #pragma unroll
    for (int d = 0; d < DH_; ++d) a += qs[qr][d] * ks[lane][d];
    a *= scale;
    float mx = a;
    #pragma unroll
    for (int off = 1; off < 64; off <<= 1) mx = fmaxf(mx, __shfl_xor(mx, off, 64));
    float e = __expf(a - mx);
    float sum = e;
    #pragma unroll
    for (int off = 1; off < 64; off <<= 1) sum += __shfl_xor(sum, off, 64);
    attn[((long)bh * 64 + qr) * 64 + lane] = f2bf(e * (1.f / sum));
  }
}

// ---------------- kernel 3: persistent pipelined fused block ----------------
// grid 256 (1 block/CU), 512 thr. Block g owns pairs P = g + p*256 (p<4; g<8: 5),
// pair P -> b=P/129, t0=2*(P%129). Two full pair-buffers ping-pong in LDS
// (132 KB): while pair p is computed from buf[p&1], pair p+1's x/musig loads
// are issued (retired free at the next barrier's vmcnt drain) and LN+ds_write
// into buf[(p+1)&1] overlaps GEMM3/epilogue. Memory flows during every phase.
__global__ __launch_bounds__(512, 2) void k3_main(
    const float* __restrict__ x, const float* __restrict__ lnw, const float* __restrict__ lnb,
    const float* __restrict__ bproj, const float* __restrict__ musig,
    const u16* __restrict__ wv, const u16* __restrict__ wp,
    const u16* __restrict__ attn, float* __restrict__ out){
  constexpr int XS = 264;            // row stride (bf16 elems); 132 dwords ≡ 4 mod 32
  constexpr int TSL = 64 * XS;       // 16896 elems per t-slice
  constexpr int PBUF = 2 * TSL;      // 33792 elems per pair buffer
  __shared__ __align__(16) u16 Xs[2 * PBUF];   // 132 KB: ping-pong pair buffers
  __shared__ float lnw_s[D_], lnb_s[D_], bp_s[D_];

  int g = blockIdx.x;                // 0..255
  int tid = threadIdx.x;
  int w = tid >> 6, lane = tid & 63, lm = lane & 15, lq = lane >> 4;
  int cw = w * 32;
  int h = w;
  int c8 = (tid & 31) * 8;
  int vrow = tid >> 5;               // 0..15: this thread's vr2 sub-index

  if (tid < 256){ lnw_s[tid] = lnw[tid]; lnb_s[tid] = lnb[tid]; bp_s[tid] = bproj[tid]; }

  int nP = (g < 8) ? 5 : 4;          // 1032 = 4*256 + 8

  float4 xa[8][2];                   // prefetched x (64 VGPR)
  float2 msv[8];                     // prefetched mu/rstd (16 VGPR)

  // ---- prologue: prefetch pair 0 ----
  {
    int P = g; int bb = P / 129, ty = P % 129, t0n = ty * 2;
    #pragma unroll
    for (int ii = 0; ii < 8; ++ii){
      int vr2 = ii * 16 + vrow;
      int tslot = vr2 >> 6, vr = vr2 & 63;
      int t = t0n + tslot;
      if (t < T1_){
        const float* gp = x + (((long)bb * V_ + vr) * T1_ + t) * D_ + c8;
        xa[ii][0] = *(const float4*)gp;
        xa[ii][1] = *(const float4*)(gp + 4);
        msv[ii] = *(const float2*)&musig[(((long)bb * V_ + vr) * T1_ + t) * 2];
      } else {
        xa[ii][0] = (float4){0.f,0.f,0.f,0.f};
        xa[ii][1] = (float4){0.f,0.f,0.f,0.f};
        msv[ii] = (float2){0.f, 1.f};
      }
    }
  }
  __syncthreads();   // lnw_s ready (and prologue loads drained)
  // LN + write pair 0 into buf0
  #pragma unroll
  for (int ii = 0; ii < 8; ++ii){
    int vr2 = ii * 16 + vrow;
    int tslot = vr2 >> 6, vr = vr2 & 63;
    float mu = msv[ii].x, rs = msv[ii].y;
    float av[8] = {xa[ii][0].x, xa[ii][0].y, xa[ii][0].z, xa[ii][0].w,
                   xa[ii][1].x, xa[ii][1].y, xa[ii][1].z, xa[ii][1].w};
    union { u16 us[8]; uint4 q4; } pk;
    #pragma unroll
    for (int j = 0; j < 8; ++j)
      pk.us[j] = f2bf((av[j] - mu) * rs * lnw_s[c8 + j] + lnb_s[c8 + j]);
    *(uint4*)&Xs[tslot * TSL + vr * XS + c8] = pk.q4;
  }
  __syncthreads();   // buf0 ready

  for (int p = 0; p < nP; ++p){
    u16* buf  = &Xs[(p & 1) * PBUF];
    u16* nbuf = &Xs[((p + 1) & 1) * PBUF];
    int P = g + p * 256;
    int b = P / 129, ty = P % 129, t0 = ty * 2;
    bool pf = (p + 1 < nP);

    // ---- GEMM1 (both slices): vf = buf @ Wv^T ----
    f32x4 acc1[2][4][2];
    #pragma unroll
    for (int tt = 0; tt < 2; ++tt)
      #pragma unroll
      for (int mt = 0; mt < 4; ++mt)
        #pragma unroll
        for (int nt = 0; nt < 2; ++nt) acc1[tt][mt][nt] = (f32x4){0.f, 0.f, 0.f, 0.f};
    for (int kk = 0; kk < 8; ++kk){
      short8 bfr[2];
      #pragma unroll
      for (int nt = 0; nt < 2; ++nt)
        bfr[nt] = *(const short8*)&wv[(long)(cw + nt * 16 + lm) * D_ + kk * 32 + lq * 8];
      #pragma unroll
      for (int tt = 0; tt < 2; ++tt){
        short8 af[4];
        #pragma unroll
        for (int mt = 0; mt < 4; ++mt)
          af[mt] = *(const short8*)&buf[tt * TSL + (mt * 16 + lm) * XS + kk * 32 + lq * 8];
        #pragma unroll
        for (int mt = 0; mt < 4; ++mt)
          #pragma unroll
          for (int nt = 0; nt < 2; ++nt)
            acc1[tt][mt][nt] = __builtin_amdgcn_mfma_f32_16x16x32_bf16(af[mt], bfr[nt], acc1[tt][mt][nt], 0, 0, 0);
      }
    }

    // ---- prefetch attn fragments (L2) then next pair's x/musig (HBM) ----
    // issued here so they retire for free at bar2's vmcnt drain.
    short8 atf[2][4];
    #pragma unroll
    for (int kk = 0; kk < 2; ++kk)
      #pragma unroll
      for (int mt = 0; mt < 4; ++mt)
        atf[kk][mt] = *(const short8*)&attn[((long)(b * H_ + h) * 64 + mt * 16 + lm) * 64 + kk * 32 + lq * 8];
    __builtin_amdgcn_sched_barrier(0);
    if (pf){
      int Pn = g + (p + 1) * 256;
      int bb = Pn / 129, tyn = Pn % 129, t0n = tyn * 2;
      #pragma unroll
      for (int ii = 0; ii < 8; ++ii){
        int vr2 = ii * 16 + vrow;
        int tslot = vr2 >> 6, vr = vr2 & 63;
        int t = t0n + tslot;
        if (t < T1_){
          const float* gp = x + (((long)bb * V_ + vr) * T1_ + t) * D_ + c8;
          xa[ii][0] = *(const float4*)gp;
          xa[ii][1] = *(const float4*)(gp + 4);
          msv[ii] = *(const float2*)&musig[(((long)bb * V_ + vr) * T1_ + t) * 2];
        } else {
          xa[ii][0] = (float4){0.f,0.f,0.f,0.f};
          xa[ii][1] = (float4){0.f,0.f,0.f,0.f};
          msv[ii] = (float2){0.f, 1.f};
        }
      }
    }

    // ---- pack acc1 -> bf16 word pairs ----
    unsigned int pw[2][4][2][2];
    #pragma unroll
    for (int tt = 0; tt < 2; ++tt)
      #pragma unroll
      for (int mt = 0; mt < 4; ++mt)
        #pragma unroll
        for (int nt = 0; nt < 2; ++nt)
          #pragma unroll
          for (int q = 0; q < 2; ++q)
            pw[tt][mt][nt][q] = (unsigned int)f2bf(acc1[tt][mt][nt][2*q])
                              | ((unsigned int)f2bf(acc1[tt][mt][nt][2*q+1]) << 16);
    __syncthreads();   // bar2: GEMM1 A-reads done -> buf reusable as VT scratch

    // ---- VT (wave-private, in dead buf): per tt, [32 cols][64 vars], XOR-swizzled ----
    u16* vtw = &buf[w * 4224];
    #pragma unroll
    for (int tt = 0; tt < 2; ++tt)
      #pragma unroll
      for (int mt = 0; mt < 4; ++mt)
        #pragma unroll
        for (int nt = 0; nt < 2; ++nt){
          int c  = nt * 16 + lm;
          int v8 = mt * 2 + (lq >> 1);
          int off = tt * 2048 + c * 64 + ((v8 ^ (lm & 7)) * 8) + (lq & 1) * 4;
          union { unsigned int wq[2]; uint2 q2; } pv;
          pv.wq[0] = pw[tt][mt][nt][0]; pv.wq[1] = pw[tt][mt][nt][1];
          *(uint2*)&vtw[off] = pv.q2;
        }

    // ---- mix (both slices): acc2 = attn_h @ vf ----
    f32x4 acc2[2][4][2];
    #pragma unroll
    for (int tt = 0; tt < 2; ++tt)
      #pragma unroll
      for (int mt = 0; mt < 4; ++mt)
        #pragma unroll
        for (int nt = 0; nt < 2; ++nt) acc2[tt][mt][nt] = (f32x4){0.f, 0.f, 0.f, 0.f};
    #pragma unroll
    for (int kk = 0; kk < 2; ++kk)
      #pragma unroll
      for (int tt = 0; tt < 2; ++tt){
        short8 bfr[2];
        #pragma unroll
        for (int nt = 0; nt < 2; ++nt){
          int c = nt * 16 + lm;
          int v8 = kk * 4 + lq;
          bfr[nt] = *(const short8*)&vtw[tt * 2048 + c * 64 + ((v8 ^ (lm & 7)) * 8)];
        }
        #pragma unroll
        for (int mt = 0; mt < 4; ++mt)
          #pragma unroll
          for (int nt = 0; nt < 2; ++nt)
            acc2[tt][mt][nt] = __builtin_amdgcn_mfma_f32_16x16x32_bf16(atf[kk][mt], bfr[nt], acc2[tt][mt][nt], 0, 0, 0);
      }
    __syncthreads();   // bar3: VT reads done -> buf reusable as Ms

    // ---- write mix into Ms (= buf), row-major ----
    #pragma unroll
    for (int tt = 0; tt < 2; ++tt)
      #pragma unroll
      for (int mt = 0; mt < 4; ++mt)
        #pragma unroll
        for (int nt = 0; nt < 2; ++nt){
          int col = h * 32 + nt * 16 + lm;
          #pragma unroll
          for (int r = 0; r < 4; ++r){
            int row = mt * 16 + lq * 4 + r;
            buf[tt * TSL + row * XS + col] = f2bf(acc2[tt][mt][nt][r]);
          }
        }
    __syncthreads();   // bar4: Ms complete

    // ---- GEMM3 (both slices): out = Ms @ Wproj^T ----
    f32x4 acc3[2][4][2];
    #pragma unroll
    for (int tt = 0; tt < 2; ++tt)
      #pragma unroll
      for (int mt = 0; mt < 4; ++mt)
        #pragma unroll
        for (int nt = 0; nt < 2; ++nt) acc3[tt][mt][nt] = (f32x4){0.f, 0.f, 0.f, 0.f};
    for (int kk = 0; kk < 8; ++kk){
      short8 bfr[2];
      #pragma unroll
      for (int nt = 0; nt < 2; ++nt)
        bfr[nt] = *(const short8*)&wp[(long)(cw + nt * 16 + lm) * D_ + kk * 32 + lq * 8];
      #pragma unroll
      for (int tt = 0; tt < 2; ++tt){
        short8 af[4];
        #pragma unroll
        for (int mt = 0; mt < 4; ++mt)
          af[mt] = *(const short8*)&buf[tt * TSL + (mt * 16 + lm) * XS + kk * 32 + lq * 8];
        #pragma unroll
        for (int mt = 0; mt < 4; ++mt)
          #pragma unroll
          for (int nt = 0; nt < 2; ++nt)
            acc3[tt][mt][nt] = __builtin_amdgcn_mfma_f32_16x16x32_bf16(af[mt], bfr[nt], acc3[tt][mt][nt], 0, 0, 0);
      }
    }

    // ---- LN + ds_write next pair into nbuf (overlaps epilogue traffic) ----
    if (pf){
      #pragma unroll
      for (int ii = 0; ii < 8; ++ii){
        int vr2 = ii * 16 + vrow;
        int tslot = vr2 >> 6, vr = vr2 & 63;
        float mu = msv[ii].x, rs = msv[ii].y;
        float av[8] = {xa[ii][0].x, xa[ii][0].y, xa[ii][0].z, xa[ii][0].w,
                       xa[ii][1].x, xa[ii][1].y, xa[ii][1].z, xa[ii][1].w};
        union { u16 us[8]; uint4 q4; } pk;
        #pragma unroll
        for (int j = 0; j < 8; ++j)
          pk.us[j] = f2bf((av[j] - mu) * rs * lnw_s[c8 + j] + lnb_s[c8 + j]);
        *(uint4*)&nbuf[tslot * TSL + vr * XS + c8] = pk.q4;
      }
    }

    // ---- epilogue: + b_proj + x, store fp32 ----
    #pragma unroll
    for (int tt = 0; tt < 2; ++tt){
      int t = t0 + tt;
      if (t < T1_){
        #pragma unroll
        for (int mt = 0; mt < 4; ++mt)
          #pragma unroll
          for (int nt = 0; nt < 2; ++nt){
            int e = cw + nt * 16 + lm;
            #pragma unroll
            for (int r = 0; r < 4; ++r){
              int vr = mt * 16 + lq * 4 + r;
              long gidx = (((long)b * V_ + vr) * T1_ + t) * D_ + e;
              out[gidx] = acc3[tt][mt][nt][r] + bp_s[e] + x[gidx];
            }
          }
      }
    }
    __syncthreads();   // barE: nbuf ready; buf fully consumed
  }
}

// ---------------- launch ----------------
extern "C" void kernel_launch(void* const* d_in, const int* in_sizes, int n_in,
                              void* d_out, int out_size, void* d_ws, size_t ws_size,
                              hipStream_t stream){
  const float* x     = (const float*)d_in[0];
  const int*   mask  = (const int*)d_in[1];
  const float* lnw   = (const float*)d_in[2];
  const float* lnb   = (const float*)d_in[3];
  const float* wqkv  = (const float*)d_in[4];
  const float* wproj = (const float*)d_in[5];
  const float* bproj = (const float*)d_in[6];
  float* out = (float*)d_out;
  char* ws = (char*)d_ws;
  float* musig = (float*)(ws);              // 263168 f
  float* xsum  = (float*)(ws + 1052672);    // 131072 f
  float* qbuf  = (float*)(ws + 1576960);    // 131072 f
  float* kbuf  = (float*)(ws + 2101248);    // 131072 f
  u16*   attn  = (u16*)  (ws + 2625536);    // 262144 u16
  u16*   wv    = (u16*)  (ws + 3149824);    // 65536 u16
  u16*   wp    = (u16*)  (ws + 3280896);    // 65536 u16

  k0_conv<<<512, 256, 0, stream>>>(wqkv, wproj, wv, wp, xsum);
  k1_ln<<<dim3(512, 4), 256, 0, stream>>>(x, mask, lnw, lnb, musig, xsum);
  k2a_qk<<<dim3(512, 4), 256, 0, stream>>>(x, mask, lnw, lnb, wqkv, musig, xsum, qbuf, kbuf);
  k2b_attn<<<64, 256, 0, stream>>>(qbuf, kbuf, attn);
  k3_main<<<256, 512, 0, stream>>>(x, lnw, lnb, bproj, musig, wv, wp, attn, out);
}

// Round 6
// 389.131 us; speedup vs baseline: 1.2689x; 1.2689x over previous
//
#include <hip/hip_runtime.h>
#include <hip/hip_bf16.h>

typedef unsigned short u16;
typedef __attribute__((ext_vector_type(8))) short short8;
typedef __attribute__((ext_vector_type(4))) float f32x4;

#define B_ 8
#define V_ 64
#define T_ 256
#define T1_ 257
#define D_ 256
#define H_ 8
#define DH_ 32

__device__ __forceinline__ u16 f2bf(float f){
  union { float f; unsigned int u; } v; v.f = f;
  unsigned int u = v.u;
  return (u16)((u + 0x7fffu + ((u >> 16) & 1u)) >> 16);
}

// ---------------- kernel 1 (fused): LN stats + masked xn-sum + q,k proj + weight conv ----------------
// grid 640, block 512. Blocks 512..639: convert Wv/Wp to bf16.
// Blocks 0..511 (one per bv): (a) scan all t: musig + masked xn accumulation
// (each half-wave owns one t); (b) block-reduce xsum IN LDS (no global round
// trip, no atomics); (c) mask count; (d) q,k projections (half-wave per output).
// Replaces old k0+k1+k2a: two fewer launches, xsum buffer eliminated.
__global__ void k1_fused(const float* __restrict__ x, const int* __restrict__ mask,
                         const float* __restrict__ lnw, const float* __restrict__ lnb,
                         const float* __restrict__ wqkv, const float* __restrict__ wproj,
                         float* __restrict__ musig, float* __restrict__ qout,
                         float* __restrict__ kout, u16* __restrict__ wv, u16* __restrict__ wp){
  if (blockIdx.x >= 512){
    int j = (blockIdx.x - 512) * 512 + threadIdx.x;   // 0..65535
    wv[j] = f2bf(wqkv[131072 + j]);
    wp[j] = f2bf(wproj[j]);
    return;
  }
  int bv = blockIdx.x;
  int tid = threadIdx.x;
  int lane = tid & 63, wid = tid >> 6;
  int half = lane >> 5, l32 = lane & 31;
  int c8 = l32 * 8;
  __shared__ float xsred[8][512];
  __shared__ float redc[8];
  __shared__ float ms0[2];
  __shared__ __align__(16) float xn0s[D_];
  __shared__ __align__(16) float xsv[D_];
  float4 w0 = *(const float4*)&lnw[c8], w1 = *(const float4*)&lnw[c8 + 4];
  float4 b0 = *(const float4*)&lnb[c8], b1 = *(const float4*)&lnb[c8 + 4];
  float xs[8];
  #pragma unroll
  for (int j = 0; j < 8; ++j) xs[j] = 0.f;
  for (int p = wid; p < 129; p += 8){
    int t = p * 2 + half;
    bool valid = (t < T1_);
    float4 a0 = {0.f,0.f,0.f,0.f}, a1 = {0.f,0.f,0.f,0.f};
    if (valid){
      const float* gp = &x[((long)bv * T1_ + t) * D_ + c8];
      a0 = *(const float4*)gp; a1 = *(const float4*)(gp + 4);
    }
    float s  = a0.x + a0.y + a0.z + a0.w + a1.x + a1.y + a1.z + a1.w;
    float s2 = a0.x*a0.x + a0.y*a0.y + a0.z*a0.z + a0.w*a0.w
             + a1.x*a1.x + a1.y*a1.y + a1.z*a1.z + a1.w*a1.w;
    #pragma unroll
    for (int off = 1; off < 32; off <<= 1){
      s  += __shfl_xor(s,  off, 64);
      s2 += __shfl_xor(s2, off, 64);
    }
    float mu   = s * (1.f / 256.f);
    float var  = s2 * (1.f / 256.f) - mu * mu;
    float rstd = rsqrtf(var + 1e-5f);
    if (valid){
      if (l32 == 0){
        musig[((long)bv * T1_ + t) * 2]     = mu;
        musig[((long)bv * T1_ + t) * 2 + 1] = rstd;
        if (t == 0){ ms0[0] = mu; ms0[1] = rstd; }
      }
      int m = (t == 0) ? 1 : mask[bv * T_ + (t - 1)];
      if (m){
        xs[0] += (a0.x - mu) * rstd * w0.x + b0.x;
        xs[1] += (a0.y - mu) * rstd * w0.y + b0.y;
        xs[2] += (a0.z - mu) * rstd * w0.z + b0.z;
        xs[3] += (a0.w - mu) * rstd * w0.w + b0.w;
        xs[4] += (a1.x - mu) * rstd * w1.x + b1.x;
        xs[5] += (a1.y - mu) * rstd * w1.y + b1.y;
        xs[6] += (a1.z - mu) * rstd * w1.z + b1.z;
        xs[7] += (a1.w - mu) * rstd * w1.w + b1.w;
      }
    }
  }
  #pragma unroll
  for (int j = 0; j < 8; ++j) xsred[wid][half * 256 + c8 + j] = xs[j];
  // mask count (each of 256 entries read once)
  int sm = (tid < 256) ? mask[bv * T_ + tid] : 0;
  #pragma unroll
  for (int off = 32; off >= 1; off >>= 1) sm += __shfl_down(sm, off, 64);
  if (lane == 0) redc[wid] = (float)sm;
  __syncthreads();
  if (tid < 256){
    float r = 0.f;
    #pragma unroll
    for (int w2 = 0; w2 < 8; ++w2) r += xsred[w2][tid] + xsred[w2][256 + tid];
    xsv[tid] = r;
    xn0s[tid] = (x[((long)bv * T1_) * D_ + tid] - ms0[0]) * ms0[1] * lnw[tid] + lnb[tid];
  }
  __syncthreads();
  float cnt = 1.f + redc[0] + redc[1] + redc[2] + redc[3]
                  + redc[4] + redc[5] + redc[6] + redc[7];
  float invc = 1.f / cnt;
  // q,k projections: half-wave hw (0..15) owns outputs e in [hw*16, hw*16+16)
  int hw = tid >> 5;
  float4 xq0 = *(const float4*)&xn0s[c8], xq1 = *(const float4*)&xn0s[c8 + 4];
  float4 xk0 = *(const float4*)&xsv[c8],  xk1 = *(const float4*)&xsv[c8 + 4];
  for (int i = 0; i < 16; ++i){
    int e = hw * 16 + i;
    const float* wq = &wqkv[(long)e * D_ + c8];
    const float* wk = &wqkv[(long)(256 + e) * D_ + c8];
    float4 q0 = *(const float4*)wq, q1 = *(const float4*)(wq + 4);
    float4 k0 = *(const float4*)wk, k1 = *(const float4*)(wk + 4);
    float sq = xq0.x*q0.x + xq0.y*q0.y + xq0.z*q0.z + xq0.w*q0.w
             + xq1.x*q1.x + xq1.y*q1.y + xq1.z*q1.z + xq1.w*q1.w;
    float sk = xk0.x*k0.x + xk0.y*k0.y + xk0.z*k0.z + xk0.w*k0.w
             + xk1.x*k1.x + xk1.y*k1.y + xk1.z*k1.z + xk1.w*k1.w;
    #pragma unroll
    for (int off = 1; off < 32; off <<= 1){
      sq += __shfl_xor(sq, off, 64);
      sk += __shfl_xor(sk, off, 64);
    }
    if (l32 == 0){
      qout[bv * D_ + e] = sq;
      kout[bv * D_ + e] = sk * invc;
    }
  }
}

// ---------------- kernel 2b: 64x64 attention per (b,h) (r1 config, best measured) ----------------
__global__ void k2b_attn(const float* __restrict__ q, const float* __restrict__ k,
                         u16* __restrict__ attn){
  int bh = blockIdx.x; int b = bh >> 3, h = bh & 7;
  int tid = threadIdx.x;
  int lane = tid & 63, wid = tid >> 6;
  __shared__ float qs[64][33], ks[64][33];
  #pragma unroll
  for (int j = 0; j < 2; ++j){
    int i4 = tid * 2 + j;
    int r = i4 >> 3, c4 = (i4 & 7) * 4;
    float4 vq = *(const float4*)&q[((long)(b * V_ + r)) * D_ + h * DH_ + c4];
    float4 vk = *(const float4*)&k[((long)(b * V_ + r)) * D_ + h * DH_ + c4];
    qs[r][c4] = vq.x; qs[r][c4+1] = vq.y; qs[r][c4+2] = vq.z; qs[r][c4+3] = vq.w;
    ks[r][c4] = vk.x; ks[r][c4+1] = vk.y; ks[r][c4+2] = vk.z; ks[r][c4+3] = vk.w;
  }
  __syncthreads();
  const float scale = 0.17677669529663687f;  // 1/sqrt(32)
  for (int i = 0; i < 16; ++i){
    int qr = i * 4 + wid;
    float a = 0.f;
    #pragma unroll
    for (int d = 0; d < DH_; ++d) a += qs[qr][d] * ks[lane][d];
    a *= scale;
    float mx = a;
    #pragma unroll
    for (int off = 1; off < 64; off <<= 1) mx = fmaxf(mx, __shfl_xor(mx, off, 64));
    float e = __expf(a - mx);
    float sum = e;
    #pragma unroll
    for (int off = 1; off < 64; off <<= 1) sum += __shfl_xor(sum, off, 64);
    attn[((long)bh * 64 + qr) * 64 + lane] = f2bf(e * (1.f / sum));
  }
}

// ---------------- kernel 3: fused block, TWO t's per block (r4, best measured) ----------------
__global__ __launch_bounds__(512, 4) void k3_main(
    const float* __restrict__ x, const float* __restrict__ lnw, const float* __restrict__ lnb,
    const float* __restrict__ bproj, const float* __restrict__ musig,
    const u16* __restrict__ wv, const u16* __restrict__ wp,
    const u16* __restrict__ attn, float* __restrict__ out){
  constexpr int XS = 264;            // row stride (bf16 elems)
  constexpr int TSL = 64 * XS;       // 16896 elems per t-slice
  __shared__ __align__(16) u16 Xs[2 * TSL];     // both xn slices; VT scratch; Ms
  __shared__ float lnw_s[D_], lnb_s[D_], bp_s[D_];
  __shared__ float ms_s[2][V_][2];

  int bt = blockIdx.x; int b = bt / 129, ty = bt % 129;
  int t0 = ty * 2;
  int tid = threadIdx.x;
  int w = tid >> 6, lane = tid & 63, lm = lane & 15, lq = lane >> 4;
  int cw = w * 32;
  int h = w;

  if (tid < 256){ lnw_s[tid] = lnw[tid]; lnb_s[tid] = lnb[tid]; bp_s[tid] = bproj[tid]; }
  else {
    int i = tid - 256;                 // 0..255
    int tslot = i >> 7, vr = (i >> 1) & 63, sel = i & 1;
    int t = t0 + tslot; if (t > 256) t = 256;   // clamp (ty=128 dual-slot)
    ms_s[tslot][vr][sel] = musig[(((long)b * V_ + vr) * T1_ + t) * 2 + sel];
  }
  __syncthreads();

  // ---- stage both x slices with LN applied, bf16, into Xs ----
  #pragma unroll
  for (int i = 0; i < 8; ++i){
    int seg = i * 512 + tid;           // 4096 segments of 8 elems
    int vr2 = seg >> 5;                // 0..127
    int tslot = vr2 >> 6, vr = vr2 & 63;
    int c8 = (seg & 31) * 8;
    int t = t0 + tslot;
    float4 a0 = {0.f,0.f,0.f,0.f}, a1 = {0.f,0.f,0.f,0.f};
    if (t < T1_){
      const float* gp = x + (((long)b * V_ + vr) * T1_ + t) * D_ + c8;
      a0 = *(const float4*)gp;
      a1 = *(const float4*)(gp + 4);
    }
    float mu = ms_s[tslot][vr][0], rs = ms_s[tslot][vr][1];
    float av[8] = {a0.x, a0.y, a0.z, a0.w, a1.x, a1.y, a1.z, a1.w};
    union { u16 us[8]; uint4 q4; } pk;
    #pragma unroll
    for (int j = 0; j < 8; ++j)
      pk.us[j] = f2bf((av[j] - mu) * rs * lnw_s[c8 + j] + lnb_s[c8 + j]);
    *(uint4*)&Xs[tslot * TSL + vr * XS + c8] = pk.q4;
  }
  __syncthreads();   // bar1: Xs complete

  // ---- GEMM1 (both slices): vf = Xs @ Wv^T ; wv fragment loaded once ----
  f32x4 acc1[2][4][2];
  #pragma unroll
  for (int tt = 0; tt < 2; ++tt)
    #pragma unroll
    for (int mt = 0; mt < 4; ++mt)
      #pragma unroll
      for (int nt = 0; nt < 2; ++nt) acc1[tt][mt][nt] = (f32x4){0.f, 0.f, 0.f, 0.f};
  for (int kk = 0; kk < 8; ++kk){
    short8 bfr[2];
    #pragma unroll
    for (int nt = 0; nt < 2; ++nt)
      bfr[nt] = *(const short8*)&wv[(long)(cw + nt * 16 + lm) * D_ + kk * 32 + lq * 8];
    #pragma unroll
    for (int tt = 0; tt < 2; ++tt){
      short8 af[4];
      #pragma unroll
      for (int mt = 0; mt < 4; ++mt)
        af[mt] = *(const short8*)&Xs[tt * TSL + (mt * 16 + lm) * XS + kk * 32 + lq * 8];
      #pragma unroll
      for (int mt = 0; mt < 4; ++mt)
        #pragma unroll
        for (int nt = 0; nt < 2; ++nt)
          acc1[tt][mt][nt] = __builtin_amdgcn_mfma_f32_16x16x32_bf16(af[mt], bfr[nt], acc1[tt][mt][nt], 0, 0, 0);
    }
  }
  // pack acc1 -> bf16 word pairs (halves live state across bar2)
  unsigned int pw[2][4][2][2];
  #pragma unroll
  for (int tt = 0; tt < 2; ++tt)
    #pragma unroll
    for (int mt = 0; mt < 4; ++mt)
      #pragma unroll
      for (int nt = 0; nt < 2; ++nt)
        #pragma unroll
        for (int p = 0; p < 2; ++p)
          pw[tt][mt][nt][p] = (unsigned int)f2bf(acc1[tt][mt][nt][2*p])
                            | ((unsigned int)f2bf(acc1[tt][mt][nt][2*p+1]) << 16);
  __syncthreads();   // bar2: all GEMM1 A-reads done -> Xs reusable as VT scratch

  // ---- VT (wave-private, in dead Xs): per tt, [32 cols][64 vars], XOR-swizzled ----
  u16* vtw = &Xs[w * 4224];            // 8.25 KB/wave region; we use 8 KB
  #pragma unroll
  for (int tt = 0; tt < 2; ++tt)
    #pragma unroll
    for (int mt = 0; mt < 4; ++mt)
      #pragma unroll
      for (int nt = 0; nt < 2; ++nt){
        int c  = nt * 16 + lm;
        int v8 = mt * 2 + (lq >> 1);
        int off = tt * 2048 + c * 64 + ((v8 ^ (lm & 7)) * 8) + (lq & 1) * 4;
        union { unsigned int wq[2]; uint2 q2; } pv;
        pv.wq[0] = pw[tt][mt][nt][0]; pv.wq[1] = pw[tt][mt][nt][1];
        *(uint2*)&vtw[off] = pv.q2;
      }

  // ---- mix (both slices): acc2 = attn_h @ vf ; attn fragments loaded once ----
  short8 atf[2][4];
  #pragma unroll
  for (int kk = 0; kk < 2; ++kk)
    #pragma unroll
    for (int mt = 0; mt < 4; ++mt)
      atf[kk][mt] = *(const short8*)&attn[((long)(b * H_ + h) * 64 + mt * 16 + lm) * 64 + kk * 32 + lq * 8];
  f32x4 acc2[2][4][2];
  #pragma unroll
  for (int tt = 0; tt < 2; ++tt)
    #pragma unroll
    for (int mt = 0; mt < 4; ++mt)
      #pragma unroll
      for (int nt = 0; nt < 2; ++nt) acc2[tt][mt][nt] = (f32x4){0.f, 0.f, 0.f, 0.f};
  #pragma unroll
  for (int kk = 0; kk < 2; ++kk)
    #pragma unroll
    for (int tt = 0; tt < 2; ++tt){
      short8 bfr[2];
      #pragma unroll
      for (int nt = 0; nt < 2; ++nt){
        int c = nt * 16 + lm;
        int v8 = kk * 4 + lq;
        bfr[nt] = *(const short8*)&vtw[tt * 2048 + c * 64 + ((v8 ^ (lm & 7)) * 8)];
      }
      #pragma unroll
      for (int mt = 0; mt < 4; ++mt)
        #pragma unroll
        for (int nt = 0; nt < 2; ++nt)
          acc2[tt][mt][nt] = __builtin_amdgcn_mfma_f32_16x16x32_bf16(atf[kk][mt], bfr[nt], acc2[tt][mt][nt], 0, 0, 0);
    }
  __syncthreads();   // bar3: all VT reads done -> Xs reusable as Ms

  // ---- write mix into Ms (= Xs), row-major; wave w -> cols [32w,32w+32) ----
  #pragma unroll
  for (int tt = 0; tt < 2; ++tt)
    #pragma unroll
    for (int mt = 0; mt < 4; ++mt)
      #pragma unroll
      for (int nt = 0; nt < 2; ++nt){
        int col = h * 32 + nt * 16 + lm;
        #pragma unroll
        for (int r = 0; r < 4; ++r){
          int row = mt * 16 + lq * 4 + r;
          Xs[tt * TSL + row * XS + col] = f2bf(acc2[tt][mt][nt][r]);
        }
      }
  __syncthreads();   // bar4: Ms complete

  // ---- GEMM3 (both slices): out = Ms @ Wproj^T ; wp fragment loaded once ----
  f32x4 acc3[2][4][2];
  #pragma unroll
  for (int tt = 0; tt < 2; ++tt)
    #pragma unroll
    for (int mt = 0; mt < 4; ++mt)
      #pragma unroll
      for (int nt = 0; nt < 2; ++nt) acc3[tt][mt][nt] = (f32x4){0.f, 0.f, 0.f, 0.f};
  for (int kk = 0; kk < 8; ++kk){
    short8 bfr[2];
    #pragma unroll
    for (int nt = 0; nt < 2; ++nt)
      bfr[nt] = *(const short8*)&wp[(long)(cw + nt * 16 + lm) * D_ + kk * 32 + lq * 8];
    #pragma unroll
    for (int tt = 0; tt < 2; ++tt){
      short8 af[4];
      #pragma unroll
      for (int mt = 0; mt < 4; ++mt)
        af[mt] = *(const short8*)&Xs[tt * TSL + (mt * 16 + lm) * XS + kk * 32 + lq * 8];
      #pragma unroll
      for (int mt = 0; mt < 4; ++mt)
        #pragma unroll
        for (int nt = 0; nt < 2; ++nt)
          acc3[tt][mt][nt] = __builtin_amdgcn_mfma_f32_16x16x32_bf16(af[mt], bfr[nt], acc3[tt][mt][nt], 0, 0, 0);
    }
  }
  // ---- epilogue: + b_proj + x, store fp32 (guard t validity) ----
  #pragma unroll
  for (int tt = 0; tt < 2; ++tt){
    int t = t0 + tt;
    if (t < T1_){
      #pragma unroll
      for (int mt = 0; mt < 4; ++mt)
        #pragma unroll
        for (int nt = 0; nt < 2; ++nt){
          int e = cw + nt * 16 + lm;
          #pragma unroll
          for (int r = 0; r < 4; ++r){
            int vr = mt * 16 + lq * 4 + r;
            long g = (((long)b * V_ + vr) * T1_ + t) * D_ + e;
            out[g] = acc3[tt][mt][nt][r] + bp_s[e] + x[g];
          }
        }
    }
  }
}

// ---------------- launch ----------------
extern "C" void kernel_launch(void* const* d_in, const int* in_sizes, int n_in,
                              void* d_out, int out_size, void* d_ws, size_t ws_size,
                              hipStream_t stream){
  const float* x     = (const float*)d_in[0];
  const int*   mask  = (const int*)d_in[1];
  const float* lnw   = (const float*)d_in[2];
  const float* lnb   = (const float*)d_in[3];
  const float* wqkv  = (const float*)d_in[4];
  const float* wproj = (const float*)d_in[5];
  const float* bproj = (const float*)d_in[6];
  float* out = (float*)d_out;
  char* ws = (char*)d_ws;
  float* musig = (float*)(ws);              // 263168 f
  float* qbuf  = (float*)(ws + 1576960);    // 131072 f
  float* kbuf  = (float*)(ws + 2101248);    // 131072 f
  u16*   attn  = (u16*)  (ws + 2625536);    // 262144 u16
  u16*   wv    = (u16*)  (ws + 3149824);    // 65536 u16
  u16*   wp    = (u16*)  (ws + 3280896);    // 65536 u16

  k1_fused<<<640, 512, 0, stream>>>(x, mask, lnw, lnb, wqkv, wproj, musig, qbuf, kbuf, wv, wp);
  k2b_attn<<<64, 256, 0, stream>>>(qbuf, kbuf, attn);
  k3_main<<<B_ * 129, 512, 0, stream>>>(x, lnw, lnb, bproj, musig, wv, wp, attn, out);
}